// Round 7
// baseline (204.642 us; speedup 1.0000x reference)
//
#include <hip/hip_runtime.h>
#include <hip/hip_bf16.h>
#include <math.h>

#define NN 50000
#define NE 800000
#define CC 64
#define GG 128
#define NB ((NN + 255) / 256)      // 196 node blocks
#define BINS ((NN + 255) / 256)    // 196 bins of 256 target nodes
#define CAPB 4608                  // bin capacity (mean 4096, +8 sigma)
#define EPB 2048                   // edges per binning block
#define GA ((NE + EPB - 1) / EPB)  // 391 binning blocks

typedef __hip_bfloat16 bf16;

// zero bin counters + stats
__global__ void k_zero(int* bin_cnt, float* stats) {
    int t = threadIdx.x;
    if (t < BINS) bin_cnt[t] = 0;
    if (t < 2 * CC) stats[t] = 0.0f;
}

// bin edges by target>>8; per-block LDS histogram, one global atomic per (block,bin)
__global__ __launch_bounds__(256) void k_binA(const int* __restrict__ ei,
                                              const float* __restrict__ w,
                                              int* __restrict__ bin_cnt,
                                              int2* __restrict__ binbuf) {
    __shared__ int hist[BINS], base[BINS], rank[BINS];
    int t = threadIdx.x;
    for (int b = t; b < BINS; b += 256) { hist[b] = 0; rank[b] = 0; }
    __syncthreads();
    int e0 = blockIdx.x * EPB;
    for (int i = t; i < EPB; i += 256) {
        int e = e0 + i;
        if (e < NE) atomicAdd(&hist[ei[NE + e] >> 8], 1);
    }
    __syncthreads();
    for (int b = t; b < BINS; b += 256)
        if (hist[b] > 0) base[b] = atomicAdd(&bin_cnt[b], hist[b]);
    __syncthreads();
    for (int i = t; i < EPB; i += 256) {
        int e = e0 + i;
        if (e >= NE) continue;
        int r = ei[e], c = ei[NE + e], b = c >> 8;
        int pos = base[b] + atomicAdd(&rank[b], 1);
        if (pos < CAPB)
            binbuf[(size_t)b * CAPB + pos] = make_int2(r | ((c & 255) << 16),
                                                       __float_as_int(w[e]));
    }
}

// one block per bin: LDS counting-sort by (target&255) -> per-node CSR (in place),
// fused weighted degree -> dinv. Zero device atomics.
__global__ __launch_bounds__(256) void k_csr(const int* __restrict__ bin_cnt,
                                             int2* __restrict__ binbuf,
                                             float* __restrict__ dinv,
                                             int* __restrict__ rps,
                                             int* __restrict__ rcnt) {
    __shared__ int2 ed[CAPB];
    __shared__ int hist[256], off[256], rank[256];
    __shared__ float degf[256];
    int g = blockIdx.x, t = threadIdx.x;
    int cnt = min(bin_cnt[g], CAPB);
    int2* bp = binbuf + (size_t)g * CAPB;
    hist[t] = 0; rank[t] = 0; degf[t] = 1.0f;   // deg starts at 1 (self-loop)
    __syncthreads();
    for (int e = t; e < cnt; e += 256) {
        int2 r = bp[e];
        ed[e] = r;
        int low = r.x >> 16;
        atomicAdd(&hist[low], 1);
        atomicAdd(&degf[low], __int_as_float(r.y));
    }
    __syncthreads();
    int v = hist[t];
    off[t] = v;
    __syncthreads();
    for (int o = 1; o < 256; o <<= 1) {        // inclusive scan
        int x = (t >= o) ? off[t - o] : 0;
        __syncthreads();
        off[t] += x;
        __syncthreads();
    }
    int node = g * 256 + t;
    if (node < NN) {
        dinv[node] = rsqrtf(degf[t]);
        rps[node] = g * CAPB + (off[t] - v);   // exclusive start
        rcnt[node] = v;
    }
    for (int e = t; e < cnt; e += 256) {
        int2 r = ed[e];
        int low = r.x >> 16;
        int pos = (off[low] - hist[low]) + atomicAdd(&rank[low], 1);
        bp[pos] = make_int2(r.x & 0xffff, r.y);
    }
}

// fold full norm into 4B records: csrc = src | bf16bits(dinv[src]*w*dinv[node])<<16
__global__ __launch_bounds__(256) void k_fold(const float* __restrict__ dinv,
                                              const int* __restrict__ rps,
                                              const int* __restrict__ rcnt,
                                              const int2* __restrict__ binbuf,
                                              unsigned* __restrict__ csrc) {
    int node = blockIdx.x * 4 + (threadIdx.x >> 6);
    int l = threadIdx.x & 63;
    if (node >= NN) return;
    float dn = dinv[node];
    int s = rps[node], n = rcnt[node];
    for (int p = l; p < n; p += 64) {
        int2 rec = binbuf[s + p];
        float nw = dinv[rec.x] * __int_as_float(rec.y) * dn;
        bf16 hb = __float2bfloat16(nw);
        unsigned short us = *reinterpret_cast<unsigned short*>(&hb);
        csrc[s + p] = (unsigned)rec.x | ((unsigned)us << 16);
    }
}

// f32 -> bf16 feature conversion
__global__ void k_cvt(const float* __restrict__ x, bf16* __restrict__ xh) {
    int t = blockIdx.x * blockDim.x + threadIdx.x;
    if (t < NN * CC) xh[t] = __float2bfloat16(x[t]);
}

// wave per node, register accumulate; bf16 rows, folded 4B records
__global__ __launch_bounds__(256) void k_hop3(const bf16* __restrict__ in,
                                              const float* __restrict__ dinv,
                                              const int* __restrict__ rps,
                                              const int* __restrict__ rcnt,
                                              const unsigned* __restrict__ csrc,
                                              bf16* __restrict__ out) {
    int node = blockIdx.x * 4 + (threadIdx.x >> 6);
    int j = threadIdx.x & 63;
    if (node >= NN) return;
    float dn = dinv[node];
    float acc = dn * dn * __bfloat162float(in[node * CC + j]);
    int s = rps[node], n = rcnt[node];
    const unsigned* cp = csrc + s;
#pragma unroll 4
    for (int p = 0; p < n; p++) {
        unsigned rec = cp[p];
        float nw = __uint_as_float(rec & 0xffff0000u);   // bf16 expand
        int src = rec & 0xffff;
        acc = fmaf(nw, __bfloat162float(in[src * CC + j]), acc);
    }
    out[node * CC + j] = __float2bfloat16(acc);
}

// h(bf16) @ W^T + b, then PReLU -> f32
__global__ __launch_bounds__(256) void k_linear(const bf16* __restrict__ h,
                                                const float* __restrict__ W,
                                                const float* __restrict__ b,
                                                const float* __restrict__ a,
                                                float* __restrict__ out) {
    __shared__ float Ws[CC * 65];
    __shared__ float hs[4][CC];
    int tid = threadIdx.x;
    for (int t = tid; t < CC * CC; t += 256) {
        int j = t >> 6, k = t & 63;
        Ws[j * 65 + k] = W[t];
    }
    int i0 = blockIdx.x * 4;
    {
        int node = i0 + (tid >> 6), k = tid & 63;
        hs[tid >> 6][k] = (node < NN) ? __bfloat162float(h[node * CC + k]) : 0.0f;
    }
    __syncthreads();
    int node = i0 + (tid >> 6);
    int j = tid & 63;
    if (node >= NN) return;
    float acc = b[j];
    const float* hr = hs[tid >> 6];
#pragma unroll
    for (int k = 0; k < CC; k++) acc += hr[k] * Ws[j * 65 + k];
    float v = acc >= 0.0f ? acc : a[j] * acc;
    out[node * CC + j] = v;
}

// per-channel sum / sumsq over all N rows
__global__ __launch_bounds__(256) void k_stats(const float* __restrict__ h,
                                               float* __restrict__ stats) {
    __shared__ float ssum[4][CC], ssq[4][CC];
    int tid = threadIdx.x, wv = tid >> 6, j = tid & 63;
    float s = 0.0f, q = 0.0f;
    for (int i = blockIdx.x * 4 + wv; i < NN; i += gridDim.x * 4) {
        float v = h[i * CC + j];
        s += v;
        q += v * v;
    }
    ssum[wv][j] = s;
    ssq[wv][j] = q;
    __syncthreads();
    if (wv == 0) {
        s = ssum[0][j] + ssum[1][j] + ssum[2][j] + ssum[3][j];
        q = ssq[0][j] + ssq[1][j] + ssq[2][j] + ssq[3][j];
        atomicAdd(&stats[j], s);
        atomicAdd(&stats[CC + j], q);
    }
}

__global__ void k_bnfin(const float* gamma, const float* beta, float* stats) {
    int j = threadIdx.x;
    if (j < CC) {
        float mean = stats[j] / (float)NN;
        float var = stats[CC + j] / (float)NN - mean * mean;
        float sc = gamma[j] * rsqrtf(var + 1e-5f);
        stats[2 * CC + j] = sc;
        stats[3 * CC + j] = beta[j] - mean * sc;
    }
}

__global__ void k_starts(const int* __restrict__ batch, int* __restrict__ starts) {
    int i = blockIdx.x * blockDim.x + threadIdx.x;
    if (i >= NN) return;
    int b = batch[i];
    int bp = (i == 0) ? -1 : batch[i - 1];
    for (int g = bp + 1; g <= b; g++) starts[g] = i;
    if (i == NN - 1) {
        for (int g = b + 1; g <= GG; g++) starts[g] = NN;
    }
}

__global__ __launch_bounds__(256) void k_pool2(const float* __restrict__ h,
                                               const float* __restrict__ stats,
                                               const int* __restrict__ starts,
                                               float* __restrict__ out) {
    __shared__ float ssum[4][CC], smax[4][CC];
    int g = blockIdx.x;
    int s = starts[g], e = starts[g + 1];
    int tid = threadIdx.x, w = tid >> 6, j = tid & 63;
    float sc = stats[2 * CC + j], sh = stats[3 * CC + j];
    float sum = 0.0f, mx = -__builtin_inff();
    for (int i = s + w; i < e; i += 4) {
        float v = fmaf(h[i * CC + j], sc, sh);
        sum += v;
        mx = fmaxf(mx, v);
    }
    ssum[w][j] = sum;
    smax[w][j] = mx;
    __syncthreads();
    if (w == 0) {
        sum = ssum[0][j] + ssum[1][j] + ssum[2][j] + ssum[3][j];
        mx = fmaxf(fmaxf(smax[0][j], smax[1][j]), fmaxf(smax[2][j], smax[3][j]));
        int n = e - s;
        out[g * 2 * CC + j] = (n > 0) ? sum / (float)n : 0.0f;
        out[g * 2 * CC + CC + j] = mx;
    }
}

extern "C" void kernel_launch(void* const* d_in, const int* in_sizes, int n_in,
                              void* d_out, int out_size, void* d_ws, size_t ws_size,
                              hipStream_t stream) {
    const float* x = (const float*)d_in[0];
    const int* ei = (const int*)d_in[1];
    const float* ew = (const float*)d_in[2];
    const int* batch = (const int*)d_in[3];
    const float* W = (const float*)d_in[4];
    const float* b = (const float*)d_in[5];
    const float* a = (const float*)d_in[6];
    const float* gamma = (const float*)d_in[7];
    const float* beta = (const float*)d_in[8];
    float* out = (float*)d_out;

    float* ws = (float*)d_ws;
    // layout (floats): dinv 50048 | rps 50048 | rcnt 50048 | bin_cnt 256 | stats 256 |
    //   starts 256 | binbuf BINS*CAPB int2 | csrc BINS*CAPB uint | xh,h1,h2 bf16 NN*CC | hl f32 NN*CC
    float* dinv = ws;
    int* rps = (int*)(ws + 50048);
    int* rcnt = (int*)(ws + 2 * 50048);
    int* bin_cnt = (int*)(ws + 3 * 50048);
    float* stats = ws + 3 * 50048 + 256;
    int* starts = (int*)(stats + 256);
    int2* binbuf = (int2*)(starts + 256);
    unsigned* csrc = (unsigned*)(binbuf + (size_t)BINS * CAPB);
    bf16* xh = (bf16*)(csrc + (size_t)BINS * CAPB);
    bf16* h1 = xh + (size_t)NN * CC;
    bf16* h2 = h1 + (size_t)NN * CC;
    float* hl = (float*)(h2 + (size_t)NN * CC);

    dim3 blk(256);
    int gH = (NN + 3) / 4;
    int gNC = (NN * CC + 255) / 256;

    k_zero<<<1, blk, 0, stream>>>(bin_cnt, stats);
    k_binA<<<GA, blk, 0, stream>>>(ei, ew, bin_cnt, binbuf);
    k_csr<<<BINS, blk, 0, stream>>>(bin_cnt, binbuf, dinv, rps, rcnt);
    k_starts<<<NB, blk, 0, stream>>>(batch, starts);
    k_fold<<<gH, blk, 0, stream>>>(dinv, rps, rcnt, binbuf, csrc);
    k_cvt<<<gNC, blk, 0, stream>>>(x, xh);

    k_hop3<<<gH, blk, 0, stream>>>(xh, dinv, rps, rcnt, csrc, h1);
    k_hop3<<<gH, blk, 0, stream>>>(h1, dinv, rps, rcnt, csrc, h2);

    k_linear<<<gH, blk, 0, stream>>>(h2, W, b, a, hl);
    k_stats<<<256, blk, 0, stream>>>(hl, stats);
    k_bnfin<<<1, 64, 0, stream>>>(gamma, beta, stats);
    k_pool2<<<GG, blk, 0, stream>>>(hl, stats, starts, out);
}

// Round 8
// 197.062 us; speedup vs baseline: 1.0385x; 1.0385x over previous
//
#include <hip/hip_runtime.h>
#include <hip/hip_bf16.h>
#include <math.h>

#define NN 50000
#define NE 800000
#define CC 64
#define GG 128
#define NB ((NN + 255) / 256)      // 196 node blocks
#define BINS ((NN + 255) / 256)    // 196 bins of 256 target nodes
#define CAPB 4608                  // bin capacity (mean 4096, +8 sigma)
#define EPB 2048                   // edges per binning block
#define GA ((NE + EPB - 1) / EPB)  // 391 binning blocks

typedef __hip_bfloat16 bf16;

// zero bin counters + stats; graph start offsets from sorted batch
__global__ void k_prep(const int* __restrict__ batch, int* bin_cnt, float* stats,
                       int* starts) {
    int i = blockIdx.x * 256 + threadIdx.x;
    if (i < BINS) bin_cnt[i] = 0;
    if (i < 2 * CC) stats[i] = 0.0f;
    if (i < NN) {
        int b = batch[i];
        int bp = (i == 0) ? -1 : batch[i - 1];
        for (int g = bp + 1; g <= b; g++) starts[g] = i;
        if (i == NN - 1)
            for (int g = b + 1; g <= GG; g++) starts[g] = NN;
    }
}

// bin edges by target>>8; single pass over ei (col staged in LDS)
__global__ __launch_bounds__(256) void k_binA(const int* __restrict__ ei,
                                              const float* __restrict__ w,
                                              int* __restrict__ bin_cnt,
                                              int2* __restrict__ binbuf) {
    __shared__ int hist[BINS], base[BINS], rank[BINS];
    __shared__ int cstg[EPB];
    int t = threadIdx.x;
    for (int b = t; b < BINS; b += 256) { hist[b] = 0; rank[b] = 0; }
    __syncthreads();
    int e0 = blockIdx.x * EPB;
    for (int i = t; i < EPB; i += 256) {
        int e = e0 + i;
        if (e < NE) {
            int c = ei[NE + e];
            cstg[i] = c;
            atomicAdd(&hist[c >> 8], 1);
        }
    }
    __syncthreads();
    for (int b = t; b < BINS; b += 256)
        if (hist[b] > 0) base[b] = atomicAdd(&bin_cnt[b], hist[b]);
    __syncthreads();
    for (int i = t; i < EPB; i += 256) {
        int e = e0 + i;
        if (e >= NE) continue;
        int r = ei[e], c = cstg[i], b = c >> 8;
        int pos = base[b] + atomicAdd(&rank[b], 1);
        if (pos < CAPB)
            binbuf[(size_t)b * CAPB + pos] = make_int2(r | ((c & 255) << 16),
                                                       __float_as_int(w[e]));
    }
}

// one block per bin: LDS counting-sort by (target&255) -> per-node CSR (in place),
// fused weighted degree -> dinv. Zero device atomics.
__global__ __launch_bounds__(256) void k_csr(const int* __restrict__ bin_cnt,
                                             int2* __restrict__ binbuf,
                                             float* __restrict__ dinv,
                                             int* __restrict__ rps,
                                             int* __restrict__ rcnt) {
    __shared__ int2 ed[CAPB];
    __shared__ int hist[256], off[256], rank[256];
    __shared__ float degf[256];
    int g = blockIdx.x, t = threadIdx.x;
    int cnt = min(bin_cnt[g], CAPB);
    int2* bp = binbuf + (size_t)g * CAPB;
    hist[t] = 0; rank[t] = 0; degf[t] = 1.0f;   // deg starts at 1 (self-loop)
    __syncthreads();
    for (int e = t; e < cnt; e += 256) {
        int2 r = bp[e];
        ed[e] = r;
        int low = r.x >> 16;
        atomicAdd(&hist[low], 1);
        atomicAdd(&degf[low], __int_as_float(r.y));
    }
    __syncthreads();
    int v = hist[t];
    off[t] = v;
    __syncthreads();
    for (int o = 1; o < 256; o <<= 1) {        // inclusive scan
        int x = (t >= o) ? off[t - o] : 0;
        __syncthreads();
        off[t] += x;
        __syncthreads();
    }
    int node = g * 256 + t;
    if (node < NN) {
        dinv[node] = rsqrtf(degf[t]);
        rps[node] = g * CAPB + (off[t] - v);   // exclusive start
        rcnt[node] = v;
    }
    for (int e = t; e < cnt; e += 256) {
        int2 r = ed[e];
        int low = r.x >> 16;
        int pos = (off[low] - hist[low]) + atomicAdd(&rank[low], 1);
        bp[pos] = make_int2(r.x & 0xffff, r.y);
    }
}

// fold norm into 4B records + convert x row to bf16 (one wave per node)
__global__ __launch_bounds__(256) void k_foldcvt(const float* __restrict__ x,
                                                 const float* __restrict__ dinv,
                                                 const int* __restrict__ rps,
                                                 const int* __restrict__ rcnt,
                                                 const int2* __restrict__ binbuf,
                                                 unsigned* __restrict__ csrc,
                                                 bf16* __restrict__ xh) {
    int node = blockIdx.x * 4 + (threadIdx.x >> 6);
    int l = threadIdx.x & 63;
    if (node >= NN) return;
    xh[node * CC + l] = __float2bfloat16(x[node * CC + l]);
    float dn = dinv[node];
    int s = rps[node], n = rcnt[node];
    for (int p = l; p < n; p += 64) {
        int2 rec = binbuf[s + p];
        float nw = dinv[rec.x] * __int_as_float(rec.y) * dn;
        bf16 hb = __float2bfloat16(nw);
        unsigned short us = *reinterpret_cast<unsigned short*>(&hb);
        csrc[s + p] = (unsigned)rec.x | ((unsigned)us << 16);
    }
}

// wave per node, register accumulate; bf16 rows, folded 4B records
__global__ __launch_bounds__(256) void k_hop3(const bf16* __restrict__ in,
                                              const float* __restrict__ dinv,
                                              const int* __restrict__ rps,
                                              const int* __restrict__ rcnt,
                                              const unsigned* __restrict__ csrc,
                                              bf16* __restrict__ out) {
    int node = blockIdx.x * 4 + (threadIdx.x >> 6);
    int j = threadIdx.x & 63;
    if (node >= NN) return;
    float dn = dinv[node];
    float acc = dn * dn * __bfloat162float(in[node * CC + j]);
    int s = rps[node], n = rcnt[node];
    const unsigned* cp = csrc + s;
#pragma unroll 4
    for (int p = 0; p < n; p++) {
        unsigned rec = cp[p];
        float nw = __uint_as_float(rec & 0xffff0000u);   // bf16 expand
        int src = rec & 0xffff;
        acc = fmaf(nw, __bfloat162float(in[src * CC + j]), acc);
    }
    out[node * CC + j] = __float2bfloat16(acc);
}

// h(bf16) @ W^T + b, PReLU -> f32 out; fused per-channel sum/sumsq partials
__global__ __launch_bounds__(256) void k_linstat(const bf16* __restrict__ h,
                                                 const float* __restrict__ W,
                                                 const float* __restrict__ b,
                                                 const float* __restrict__ a,
                                                 float* __restrict__ out,
                                                 float* __restrict__ stats) {
    __shared__ float Ws[CC * 65];
    __shared__ float hs[4][CC];
    __shared__ float red[4][CC];
    int tid = threadIdx.x, wv = tid >> 6, j = tid & 63;
    for (int t = tid; t < CC * CC; t += 256)
        Ws[(t >> 6) * 65 + (t & 63)] = W[t];
    float bs = b[j], as = a[j];
    float s = 0.0f, q = 0.0f;
    for (int i0 = blockIdx.x * 4; i0 < NN; i0 += 256 * 4) {
        int node = i0 + wv;
        __syncthreads();   // previous-iter readers done before overwrite
        hs[wv][j] = (node < NN) ? __bfloat162float(h[node * CC + j]) : 0.0f;
        __syncthreads();
        if (node < NN) {
            float acc = bs;
            const float* hr = hs[wv];
#pragma unroll
            for (int k = 0; k < CC; k++) acc += hr[k] * Ws[j * 65 + k];
            float v = acc >= 0.0f ? acc : as * acc;
            out[node * CC + j] = v;
            s += v;
            q += v * v;
        }
    }
    red[wv][j] = s;
    __syncthreads();
    if (wv == 0) {
        s = red[0][j] + red[1][j] + red[2][j] + red[3][j];
        atomicAdd(&stats[j], s);
    }
    __syncthreads();
    red[wv][j] = q;
    __syncthreads();
    if (wv == 0) {
        q = red[0][j] + red[1][j] + red[2][j] + red[3][j];
        atomicAdd(&stats[CC + j], q);
    }
}

// one block per graph: BN scale/shift inline + mean/max over contiguous range
__global__ __launch_bounds__(256) void k_pool2(const float* __restrict__ h,
                                               const float* __restrict__ stats,
                                               const float* __restrict__ gamma,
                                               const float* __restrict__ beta,
                                               const int* __restrict__ starts,
                                               float* __restrict__ out) {
    __shared__ float ssum[4][CC], smax[4][CC];
    int g = blockIdx.x;
    int s = starts[g], e = starts[g + 1];
    int tid = threadIdx.x, w = tid >> 6, j = tid & 63;
    float mean = stats[j] * (1.0f / NN);
    float var = stats[CC + j] * (1.0f / NN) - mean * mean;
    float sc = gamma[j] * rsqrtf(var + 1e-5f);
    float sh = beta[j] - mean * sc;
    float sum = 0.0f, mx = -__builtin_inff();
    for (int i = s + w; i < e; i += 4) {
        float v = fmaf(h[i * CC + j], sc, sh);
        sum += v;
        mx = fmaxf(mx, v);
    }
    ssum[w][j] = sum;
    smax[w][j] = mx;
    __syncthreads();
    if (w == 0) {
        sum = ssum[0][j] + ssum[1][j] + ssum[2][j] + ssum[3][j];
        mx = fmaxf(fmaxf(smax[0][j], smax[1][j]), fmaxf(smax[2][j], smax[3][j]));
        int n = e - s;
        out[g * 2 * CC + j] = (n > 0) ? sum / (float)n : 0.0f;
        out[g * 2 * CC + CC + j] = mx;
    }
}

extern "C" void kernel_launch(void* const* d_in, const int* in_sizes, int n_in,
                              void* d_out, int out_size, void* d_ws, size_t ws_size,
                              hipStream_t stream) {
    const float* x = (const float*)d_in[0];
    const int* ei = (const int*)d_in[1];
    const float* ew = (const float*)d_in[2];
    const int* batch = (const int*)d_in[3];
    const float* W = (const float*)d_in[4];
    const float* b = (const float*)d_in[5];
    const float* a = (const float*)d_in[6];
    const float* gamma = (const float*)d_in[7];
    const float* beta = (const float*)d_in[8];
    float* out = (float*)d_out;

    float* ws = (float*)d_ws;
    float* dinv = ws;
    int* rps = (int*)(ws + 50048);
    int* rcnt = (int*)(ws + 2 * 50048);
    int* bin_cnt = (int*)(ws + 3 * 50048);
    float* stats = ws + 3 * 50048 + 256;
    int* starts = (int*)(stats + 256);
    int2* binbuf = (int2*)(starts + 256);
    unsigned* csrc = (unsigned*)(binbuf + (size_t)BINS * CAPB);
    bf16* xh = (bf16*)(csrc + (size_t)BINS * CAPB);
    bf16* h1 = xh + (size_t)NN * CC;
    bf16* h2 = h1 + (size_t)NN * CC;
    float* hl = (float*)(h2 + (size_t)NN * CC);

    dim3 blk(256);
    int gH = (NN + 3) / 4;

    k_prep<<<NB, blk, 0, stream>>>(batch, bin_cnt, stats, starts);
    k_binA<<<GA, blk, 0, stream>>>(ei, ew, bin_cnt, binbuf);
    k_csr<<<BINS, blk, 0, stream>>>(bin_cnt, binbuf, dinv, rps, rcnt);
    k_foldcvt<<<gH, blk, 0, stream>>>(x, dinv, rps, rcnt, binbuf, csrc, xh);

    k_hop3<<<gH, blk, 0, stream>>>(xh, dinv, rps, rcnt, csrc, h1);
    k_hop3<<<gH, blk, 0, stream>>>(h1, dinv, rps, rcnt, csrc, h2);

    k_linstat<<<256, blk, 0, stream>>>(h2, W, b, a, hl, stats);
    k_pool2<<<GG, blk, 0, stream>>>(hl, stats, gamma, beta, starts, out);
}

// Round 9
// 184.607 us; speedup vs baseline: 1.1085x; 1.0675x over previous
//
#include <hip/hip_runtime.h>
#include <hip/hip_bf16.h>
#include <math.h>

#define NN 50000
#define NE 800000
#define CC 64
#define GG 128
#define NB ((NN + 255) / 256)      // 196 node blocks
#define BINS ((NN + 255) / 256)    // 196 bins of 256 target nodes
#define CAPB 4608                  // bin capacity (mean 4096, +8 sigma)
#define EPB 2048                   // edges per binning block
#define GA ((NE + EPB - 1) / EPB)  // 391 binning blocks

typedef __hip_bfloat16 bf16;

// zero bin counters + stats; graph start offsets from sorted batch
__global__ void k_prep(const int* __restrict__ batch, int* bin_cnt, float* stats,
                       int* starts) {
    int i = blockIdx.x * 256 + threadIdx.x;
    if (i < BINS) bin_cnt[i] = 0;
    if (i < 2 * CC) stats[i] = 0.0f;
    if (i < NN) {
        int b = batch[i];
        int bp = (i == 0) ? -1 : batch[i - 1];
        for (int g = bp + 1; g <= b; g++) starts[g] = i;
        if (i == NN - 1)
            for (int g = b + 1; g <= GG; g++) starts[g] = NN;
    }
}

// bin edges by target>>8; single pass over ei (col staged in LDS)
__global__ __launch_bounds__(256) void k_binA(const int* __restrict__ ei,
                                              const float* __restrict__ w,
                                              int* __restrict__ bin_cnt,
                                              int2* __restrict__ binbuf) {
    __shared__ int hist[BINS], base[BINS], rank[BINS];
    __shared__ int cstg[EPB];
    int t = threadIdx.x;
    for (int b = t; b < BINS; b += 256) { hist[b] = 0; rank[b] = 0; }
    __syncthreads();
    int e0 = blockIdx.x * EPB;
    for (int i = t; i < EPB; i += 256) {
        int e = e0 + i;
        if (e < NE) {
            int c = ei[NE + e];
            cstg[i] = c;
            atomicAdd(&hist[c >> 8], 1);
        }
    }
    __syncthreads();
    for (int b = t; b < BINS; b += 256)
        if (hist[b] > 0) base[b] = atomicAdd(&bin_cnt[b], hist[b]);
    __syncthreads();
    for (int i = t; i < EPB; i += 256) {
        int e = e0 + i;
        if (e >= NE) continue;
        int r = ei[e], c = cstg[i], b = c >> 8;
        int pos = base[b] + atomicAdd(&rank[b], 1);
        if (pos < CAPB)
            binbuf[(size_t)b * CAPB + pos] = make_int2(r | ((c & 255) << 16),
                                                       __float_as_int(w[e]));
    }
}

// one block per bin: LDS counting-sort by (target&255) -> per-node CSR (in place),
// fused weighted degree -> dinv. Zero device atomics.
__global__ __launch_bounds__(256) void k_csr(const int* __restrict__ bin_cnt,
                                             int2* __restrict__ binbuf,
                                             float* __restrict__ dinv,
                                             int* __restrict__ rps,
                                             int* __restrict__ rcnt) {
    __shared__ int2 ed[CAPB];
    __shared__ int hist[256], off[256], rank[256];
    __shared__ float degf[256];
    int g = blockIdx.x, t = threadIdx.x;
    int cnt = min(bin_cnt[g], CAPB);
    int2* bp = binbuf + (size_t)g * CAPB;
    hist[t] = 0; rank[t] = 0; degf[t] = 1.0f;   // deg starts at 1 (self-loop)
    __syncthreads();
    for (int e = t; e < cnt; e += 256) {
        int2 r = bp[e];
        ed[e] = r;
        int low = r.x >> 16;
        atomicAdd(&hist[low], 1);
        atomicAdd(&degf[low], __int_as_float(r.y));
    }
    __syncthreads();
    int v = hist[t];
    off[t] = v;
    __syncthreads();
    for (int o = 1; o < 256; o <<= 1) {        // inclusive scan
        int x = (t >= o) ? off[t - o] : 0;
        __syncthreads();
        off[t] += x;
        __syncthreads();
    }
    int node = g * 256 + t;
    if (node < NN) {
        dinv[node] = rsqrtf(degf[t]);
        rps[node] = g * CAPB + (off[t] - v);   // exclusive start
        rcnt[node] = v;
    }
    for (int e = t; e < cnt; e += 256) {
        int2 r = ed[e];
        int low = r.x >> 16;
        int pos = (off[low] - hist[low]) + atomicAdd(&rank[low], 1);
        bp[pos] = make_int2(r.x & 0xffff, r.y);
    }
}

// y = x @ W^T (bf16, no bias — bias commutes past the hops) + fold norm records
__global__ __launch_bounds__(256) void k_linfold(const float* __restrict__ x,
                                                 const float* __restrict__ W,
                                                 const float* __restrict__ dinv,
                                                 const int* __restrict__ rps,
                                                 const int* __restrict__ rcnt,
                                                 const int2* __restrict__ binbuf,
                                                 unsigned* __restrict__ csrc,
                                                 bf16* __restrict__ y) {
    __shared__ float Ws[CC * 65];
    __shared__ float hs[4][CC];
    int tid = threadIdx.x, wv = tid >> 6, j = tid & 63;
    for (int t = tid; t < CC * CC; t += 256)
        Ws[(t >> 6) * 65 + (t & 63)] = W[t];
    int node = blockIdx.x * 4 + wv;
    hs[wv][j] = (node < NN) ? x[node * CC + j] : 0.0f;
    __syncthreads();
    if (node >= NN) return;
    float acc = 0.0f;
    const float* hr = hs[wv];
#pragma unroll
    for (int k = 0; k < CC; k++) acc += hr[k] * Ws[j * 65 + k];
    y[node * CC + j] = __float2bfloat16(acc);
    // fold: csrc = src | bf16bits(dinv[src]*w*dinv[node])<<16
    float dn = dinv[node];
    int s = rps[node], n = rcnt[node];
    for (int p = j; p < n; p += 64) {
        int2 rec = binbuf[s + p];
        float nw = dinv[rec.x] * __int_as_float(rec.y) * dn;
        bf16 hb = __float2bfloat16(nw);
        unsigned short us = *reinterpret_cast<unsigned short*>(&hb);
        csrc[s + p] = (unsigned)rec.x | ((unsigned)us << 16);
    }
}

// wave per node, register accumulate; bf16 rows, folded 4B records
__global__ __launch_bounds__(256) void k_hop3(const bf16* __restrict__ in,
                                              const float* __restrict__ dinv,
                                              const int* __restrict__ rps,
                                              const int* __restrict__ rcnt,
                                              const unsigned* __restrict__ csrc,
                                              bf16* __restrict__ out) {
    int node = blockIdx.x * 4 + (threadIdx.x >> 6);
    int j = threadIdx.x & 63;
    if (node >= NN) return;
    float dn = dinv[node];
    float acc = dn * dn * __bfloat162float(in[node * CC + j]);
    int s = rps[node], n = rcnt[node];
    const unsigned* cp = csrc + s;
#pragma unroll 4
    for (int p = 0; p < n; p++) {
        unsigned rec = cp[p];
        float nw = __uint_as_float(rec & 0xffff0000u);   // bf16 expand
        int src = rec & 0xffff;
        acc = fmaf(nw, __bfloat162float(in[src * CC + j]), acc);
    }
    out[node * CC + j] = __float2bfloat16(acc);
}

// streaming: v = PReLU(h2 + b); per-channel sum/sumsq partials -> atomics
__global__ __launch_bounds__(256) void k_stats2(const bf16* __restrict__ h,
                                                const float* __restrict__ b,
                                                const float* __restrict__ a,
                                                float* __restrict__ stats) {
    __shared__ float red[4][CC];
    int tid = threadIdx.x, wv = tid >> 6, j = tid & 63;
    float bs = b[j], as = a[j];
    float s = 0.0f, q = 0.0f;
    for (int i = blockIdx.x * 4 + wv; i < NN; i += gridDim.x * 4) {
        float v = __bfloat162float(h[i * CC + j]) + bs;
        v = v >= 0.0f ? v : as * v;
        s += v;
        q += v * v;
    }
    red[wv][j] = s;
    __syncthreads();
    if (wv == 0) {
        s = red[0][j] + red[1][j] + red[2][j] + red[3][j];
        atomicAdd(&stats[j], s);
    }
    __syncthreads();
    red[wv][j] = q;
    __syncthreads();
    if (wv == 0) {
        q = red[0][j] + red[1][j] + red[2][j] + red[3][j];
        atomicAdd(&stats[CC + j], q);
    }
}

// one block per graph: recompute v = PReLU(h2+b), BN inline, mean/max pooling
__global__ __launch_bounds__(256) void k_pool3(const bf16* __restrict__ h,
                                               const float* __restrict__ stats,
                                               const float* __restrict__ bvec,
                                               const float* __restrict__ a,
                                               const float* __restrict__ gamma,
                                               const float* __restrict__ beta,
                                               const int* __restrict__ starts,
                                               float* __restrict__ out) {
    __shared__ float ssum[4][CC], smax[4][CC];
    int g = blockIdx.x;
    int s = starts[g], e = starts[g + 1];
    int tid = threadIdx.x, w = tid >> 6, j = tid & 63;
    float bs = bvec[j], as = a[j];
    float mean = stats[j] * (1.0f / NN);
    float var = stats[CC + j] * (1.0f / NN) - mean * mean;
    float sc = gamma[j] * rsqrtf(var + 1e-5f);
    float sh = beta[j] - mean * sc;
    float sum = 0.0f, mx = -__builtin_inff();
    for (int i = s + w; i < e; i += 4) {
        float v0 = __bfloat162float(h[i * CC + j]) + bs;
        v0 = v0 >= 0.0f ? v0 : as * v0;
        float v = fmaf(v0, sc, sh);
        sum += v;
        mx = fmaxf(mx, v);
    }
    ssum[w][j] = sum;
    smax[w][j] = mx;
    __syncthreads();
    if (w == 0) {
        sum = ssum[0][j] + ssum[1][j] + ssum[2][j] + ssum[3][j];
        mx = fmaxf(fmaxf(smax[0][j], smax[1][j]), fmaxf(smax[2][j], smax[3][j]));
        int n = e - s;
        out[g * 2 * CC + j] = (n > 0) ? sum / (float)n : 0.0f;
        out[g * 2 * CC + CC + j] = mx;
    }
}

extern "C" void kernel_launch(void* const* d_in, const int* in_sizes, int n_in,
                              void* d_out, int out_size, void* d_ws, size_t ws_size,
                              hipStream_t stream) {
    const float* x = (const float*)d_in[0];
    const int* ei = (const int*)d_in[1];
    const float* ew = (const float*)d_in[2];
    const int* batch = (const int*)d_in[3];
    const float* W = (const float*)d_in[4];
    const float* b = (const float*)d_in[5];
    const float* a = (const float*)d_in[6];
    const float* gamma = (const float*)d_in[7];
    const float* beta = (const float*)d_in[8];
    float* out = (float*)d_out;

    float* ws = (float*)d_ws;
    float* dinv = ws;
    int* rps = (int*)(ws + 50048);
    int* rcnt = (int*)(ws + 2 * 50048);
    int* bin_cnt = (int*)(ws + 3 * 50048);
    float* stats = ws + 3 * 50048 + 256;
    int* starts = (int*)(stats + 256);
    int2* binbuf = (int2*)(starts + 256);
    unsigned* csrc = (unsigned*)(binbuf + (size_t)BINS * CAPB);
    bf16* y = (bf16*)(csrc + (size_t)BINS * CAPB);
    bf16* h1 = y + (size_t)NN * CC;
    bf16* h2 = h1 + (size_t)NN * CC;

    dim3 blk(256);
    int gH = (NN + 3) / 4;

    k_prep<<<NB, blk, 0, stream>>>(batch, bin_cnt, stats, starts);
    k_binA<<<GA, blk, 0, stream>>>(ei, ew, bin_cnt, binbuf);
    k_csr<<<BINS, blk, 0, stream>>>(bin_cnt, binbuf, dinv, rps, rcnt);
    k_linfold<<<gH, blk, 0, stream>>>(x, W, dinv, rps, rcnt, binbuf, csrc, y);

    k_hop3<<<gH, blk, 0, stream>>>(y, dinv, rps, rcnt, csrc, h1);
    k_hop3<<<gH, blk, 0, stream>>>(h1, dinv, rps, rcnt, csrc, h2);

    k_stats2<<<256, blk, 0, stream>>>(h2, b, a, stats);
    k_pool3<<<GG, blk, 0, stream>>>(h2, stats, b, a, gamma, beta, starts, out);
}

// Round 10
// 176.661 us; speedup vs baseline: 1.1584x; 1.0450x over previous
//
#include <hip/hip_runtime.h>
#include <hip/hip_bf16.h>
#include <math.h>

#define NN 50000
#define NE 800000
#define CC 64
#define GG 128
#define NB ((NN + 255) / 256)      // 196 node blocks
#define BINS ((NN + 255) / 256)    // 196 bins of 256 target nodes
#define CAPB 4608                  // bin capacity (mean 4096, +8 sigma)
#define EPB 2048                   // edges per binning block
#define GA ((NE + EPB - 1) / EPB)  // 391 binning blocks

typedef __hip_bfloat16 bf16;

__device__ inline float b2f(unsigned short u) {
    unsigned v = ((unsigned)u) << 16;
    return __uint_as_float(v);
}
__device__ inline unsigned short f2b(float f) {
    bf16 h = __float2bfloat16(f);
    return *reinterpret_cast<unsigned short*>(&h);
}

// zero bin counters + stats; graph start offsets from sorted batch
__global__ void k_prep(const int* __restrict__ batch, int* bin_cnt, float* stats,
                       int* starts) {
    int i = blockIdx.x * 256 + threadIdx.x;
    if (i < BINS) bin_cnt[i] = 0;
    if (i < 2 * CC) stats[i] = 0.0f;
    if (i < NN) {
        int b = batch[i];
        int bp = (i == 0) ? -1 : batch[i - 1];
        for (int g = bp + 1; g <= b; g++) starts[g] = i;
        if (i == NN - 1)
            for (int g = b + 1; g <= GG; g++) starts[g] = NN;
    }
}

// bin edges by target>>8; single pass over ei (col staged in LDS)
__global__ __launch_bounds__(256) void k_binA(const int* __restrict__ ei,
                                              const float* __restrict__ w,
                                              int* __restrict__ bin_cnt,
                                              int2* __restrict__ binbuf) {
    __shared__ int hist[BINS], base[BINS], rank[BINS];
    __shared__ int cstg[EPB];
    int t = threadIdx.x;
    for (int b = t; b < BINS; b += 256) { hist[b] = 0; rank[b] = 0; }
    __syncthreads();
    int e0 = blockIdx.x * EPB;
    for (int i = t; i < EPB; i += 256) {
        int e = e0 + i;
        if (e < NE) {
            int c = ei[NE + e];
            cstg[i] = c;
            atomicAdd(&hist[c >> 8], 1);
        }
    }
    __syncthreads();
    for (int b = t; b < BINS; b += 256)
        if (hist[b] > 0) base[b] = atomicAdd(&bin_cnt[b], hist[b]);
    __syncthreads();
    for (int i = t; i < EPB; i += 256) {
        int e = e0 + i;
        if (e >= NE) continue;
        int r = ei[e], c = cstg[i], b = c >> 8;
        int pos = base[b] + atomicAdd(&rank[b], 1);
        if (pos < CAPB)
            binbuf[(size_t)b * CAPB + pos] = make_int2(r | ((c & 255) << 16),
                                                       __float_as_int(w[e]));
    }
}

// one block per bin: LDS counting-sort by (target&255) -> per-node CSR (in place),
// fused weighted degree -> dinv. Zero device atomics.
__global__ __launch_bounds__(256) void k_csr(const int* __restrict__ bin_cnt,
                                             int2* __restrict__ binbuf,
                                             float* __restrict__ dinv,
                                             int* __restrict__ rps,
                                             int* __restrict__ rcnt) {
    __shared__ int2 ed[CAPB];
    __shared__ int hist[256], off[256], rank[256];
    __shared__ float degf[256];
    int g = blockIdx.x, t = threadIdx.x;
    int cnt = min(bin_cnt[g], CAPB);
    int2* bp = binbuf + (size_t)g * CAPB;
    hist[t] = 0; rank[t] = 0; degf[t] = 1.0f;   // deg starts at 1 (self-loop)
    __syncthreads();
    for (int e = t; e < cnt; e += 256) {
        int2 r = bp[e];
        ed[e] = r;
        int low = r.x >> 16;
        atomicAdd(&hist[low], 1);
        atomicAdd(&degf[low], __int_as_float(r.y));
    }
    __syncthreads();
    int v = hist[t];
    off[t] = v;
    __syncthreads();
    for (int o = 1; o < 256; o <<= 1) {        // inclusive scan
        int x = (t >= o) ? off[t - o] : 0;
        __syncthreads();
        off[t] += x;
        __syncthreads();
    }
    int node = g * 256 + t;
    if (node < NN) {
        dinv[node] = rsqrtf(degf[t]);
        rps[node] = g * CAPB + (off[t] - v);   // exclusive start
        rcnt[node] = v;
    }
    for (int e = t; e < cnt; e += 256) {
        int2 r = ed[e];
        int low = r.x >> 16;
        int pos = (off[low] - hist[low]) + atomicAdd(&rank[low], 1);
        bp[pos] = make_int2(r.x & 0xffff, r.y);
    }
}

// y = x @ W^T (bf16, no bias — bias commutes past the hops) + fold norm records
__global__ __launch_bounds__(256) void k_linfold(const float* __restrict__ x,
                                                 const float* __restrict__ W,
                                                 const float* __restrict__ dinv,
                                                 const int* __restrict__ rps,
                                                 const int* __restrict__ rcnt,
                                                 const int2* __restrict__ binbuf,
                                                 unsigned* __restrict__ csrc,
                                                 bf16* __restrict__ y) {
    __shared__ float Ws[CC * 65];
    __shared__ float hs[4][CC];
    int tid = threadIdx.x, wv = tid >> 6, j = tid & 63;
    for (int t = tid; t < CC * CC; t += 256)
        Ws[(t >> 6) * 65 + (t & 63)] = W[t];
    int node = blockIdx.x * 4 + wv;
    hs[wv][j] = (node < NN) ? x[node * CC + j] : 0.0f;
    __syncthreads();
    if (node >= NN) return;
    float acc = 0.0f;
    const float* hr = hs[wv];
#pragma unroll
    for (int k = 0; k < CC; k++) acc += hr[k] * Ws[j * 65 + k];
    y[node * CC + j] = __float2bfloat16(acc);
    // fold: csrc = src | bf16bits(dinv[src]*w*dinv[node])<<16
    float dn = dinv[node];
    int s = rps[node], n = rcnt[node];
    for (int p = j; p < n; p += 64) {
        int2 rec = binbuf[s + p];
        float nw = dinv[rec.x] * __int_as_float(rec.y) * dn;
        csrc[s + p] = (unsigned)rec.x | ((unsigned)f2b(nw) << 16);
    }
}

// wave per node, 2 edges per iteration: half-wave (32 lanes x ushort2) per edge.
// ~8 gathers in flight per wave (unroll 4 x 2 halves).
__global__ __launch_bounds__(256) void k_hop4(const bf16* __restrict__ in,
                                              const float* __restrict__ dinv,
                                              const int* __restrict__ rps,
                                              const int* __restrict__ rcnt,
                                              const unsigned* __restrict__ csrc,
                                              bf16* __restrict__ out) {
    int node = blockIdx.x * 4 + (threadIdx.x >> 6);
    if (node >= NN) return;
    int lane = threadIdx.x & 63;
    int half = lane >> 5;          // 0 or 1: which edge of the pair
    int lc = lane & 31;            // channel-pair index (channels 2lc, 2lc+1)
    float dn = dinv[node];
    // self-loop: half 0 only (halves are summed at the end)
    ushort2 sv = *reinterpret_cast<const ushort2*>(&in[node * CC + 2 * lc]);
    float ax = half ? 0.0f : dn * dn * b2f(sv.x);
    float ay = half ? 0.0f : dn * dn * b2f(sv.y);
    int s = rps[node], n = rcnt[node];
    const unsigned* cp = csrc + s;
    int p = 0;
#pragma unroll 4
    for (; p + 2 <= n; p += 2) {
        unsigned rec = cp[p + half];
        float nw = __uint_as_float(rec & 0xffff0000u);   // bf16 expand
        int src = rec & 0xffff;
        ushort2 v = *reinterpret_cast<const ushort2*>(&in[src * CC + 2 * lc]);
        ax = fmaf(nw, b2f(v.x), ax);
        ay = fmaf(nw, b2f(v.y), ay);
    }
    if (p < n && half == 0) {      // odd tail edge
        unsigned rec = cp[p];
        float nw = __uint_as_float(rec & 0xffff0000u);
        int src = rec & 0xffff;
        ushort2 v = *reinterpret_cast<const ushort2*>(&in[src * CC + 2 * lc]);
        ax = fmaf(nw, b2f(v.x), ax);
        ay = fmaf(nw, b2f(v.y), ay);
    }
    // combine the two halves
    ax += __shfl_xor(ax, 32, 64);
    ay += __shfl_xor(ay, 32, 64);
    if (half == 0) {
        ushort2 ov = make_ushort2(f2b(ax), f2b(ay));
        *reinterpret_cast<ushort2*>(&out[node * CC + 2 * lc]) = ov;
    }
}

// streaming: v = PReLU(h2 + b); per-channel sum/sumsq partials -> atomics
__global__ __launch_bounds__(256) void k_stats2(const bf16* __restrict__ h,
                                                const float* __restrict__ b,
                                                const float* __restrict__ a,
                                                float* __restrict__ stats) {
    __shared__ float red[4][CC];
    int tid = threadIdx.x, wv = tid >> 6, j = tid & 63;
    float bs = b[j], as = a[j];
    float s = 0.0f, q = 0.0f;
    for (int i = blockIdx.x * 4 + wv; i < NN; i += gridDim.x * 4) {
        float v = __bfloat162float(h[i * CC + j]) + bs;
        v = v >= 0.0f ? v : as * v;
        s += v;
        q += v * v;
    }
    red[wv][j] = s;
    __syncthreads();
    if (wv == 0) {
        s = red[0][j] + red[1][j] + red[2][j] + red[3][j];
        atomicAdd(&stats[j], s);
    }
    __syncthreads();
    red[wv][j] = q;
    __syncthreads();
    if (wv == 0) {
        q = red[0][j] + red[1][j] + red[2][j] + red[3][j];
        atomicAdd(&stats[CC + j], q);
    }
}

// one block per graph: recompute v = PReLU(h2+b), BN inline, mean/max pooling
__global__ __launch_bounds__(256) void k_pool3(const bf16* __restrict__ h,
                                               const float* __restrict__ stats,
                                               const float* __restrict__ bvec,
                                               const float* __restrict__ a,
                                               const float* __restrict__ gamma,
                                               const float* __restrict__ beta,
                                               const int* __restrict__ starts,
                                               float* __restrict__ out) {
    __shared__ float ssum[4][CC], smax[4][CC];
    int g = blockIdx.x;
    int s = starts[g], e = starts[g + 1];
    int tid = threadIdx.x, w = tid >> 6, j = tid & 63;
    float bs = bvec[j], as = a[j];
    float mean = stats[j] * (1.0f / NN);
    float var = stats[CC + j] * (1.0f / NN) - mean * mean;
    float sc = gamma[j] * rsqrtf(var + 1e-5f);
    float sh = beta[j] - mean * sc;
    float sum = 0.0f, mx = -__builtin_inff();
    for (int i = s + w; i < e; i += 4) {
        float v0 = __bfloat162float(h[i * CC + j]) + bs;
        v0 = v0 >= 0.0f ? v0 : as * v0;
        float v = fmaf(v0, sc, sh);
        sum += v;
        mx = fmaxf(mx, v);
    }
    ssum[w][j] = sum;
    smax[w][j] = mx;
    __syncthreads();
    if (w == 0) {
        sum = ssum[0][j] + ssum[1][j] + ssum[2][j] + ssum[3][j];
        mx = fmaxf(fmaxf(smax[0][j], smax[1][j]), fmaxf(smax[2][j], smax[3][j]));
        int n = e - s;
        out[g * 2 * CC + j] = (n > 0) ? sum / (float)n : 0.0f;
        out[g * 2 * CC + CC + j] = mx;
    }
}

extern "C" void kernel_launch(void* const* d_in, const int* in_sizes, int n_in,
                              void* d_out, int out_size, void* d_ws, size_t ws_size,
                              hipStream_t stream) {
    const float* x = (const float*)d_in[0];
    const int* ei = (const int*)d_in[1];
    const float* ew = (const float*)d_in[2];
    const int* batch = (const int*)d_in[3];
    const float* W = (const float*)d_in[4];
    const float* b = (const float*)d_in[5];
    const float* a = (const float*)d_in[6];
    const float* gamma = (const float*)d_in[7];
    const float* beta = (const float*)d_in[8];
    float* out = (float*)d_out;

    float* ws = (float*)d_ws;
    float* dinv = ws;
    int* rps = (int*)(ws + 50048);
    int* rcnt = (int*)(ws + 2 * 50048);
    int* bin_cnt = (int*)(ws + 3 * 50048);
    float* stats = ws + 3 * 50048 + 256;
    int* starts = (int*)(stats + 256);
    int2* binbuf = (int2*)(starts + 256);
    unsigned* csrc = (unsigned*)(binbuf + (size_t)BINS * CAPB);
    bf16* y = (bf16*)(csrc + (size_t)BINS * CAPB);
    bf16* h1 = y + (size_t)NN * CC;
    bf16* h2 = h1 + (size_t)NN * CC;

    dim3 blk(256);
    int gH = (NN + 3) / 4;

    k_prep<<<NB, blk, 0, stream>>>(batch, bin_cnt, stats, starts);
    k_binA<<<GA, blk, 0, stream>>>(ei, ew, bin_cnt, binbuf);
    k_csr<<<BINS, blk, 0, stream>>>(bin_cnt, binbuf, dinv, rps, rcnt);
    k_linfold<<<gH, blk, 0, stream>>>(x, W, dinv, rps, rcnt, binbuf, csrc, y);

    k_hop4<<<gH, blk, 0, stream>>>(y, dinv, rps, rcnt, csrc, h1);
    k_hop4<<<gH, blk, 0, stream>>>(h1, dinv, rps, rcnt, csrc, h2);

    k_stats2<<<256, blk, 0, stream>>>(h2, b, a, stats);
    k_pool3<<<GG, blk, 0, stream>>>(h2, stats, b, a, gamma, beta, starts, out);
}

// Round 11
// 153.630 us; speedup vs baseline: 1.3320x; 1.1499x over previous
//
#include <hip/hip_runtime.h>
#include <hip/hip_bf16.h>
#include <math.h>

#define NN 50000
#define NE 800000
#define CC 64
#define GG 128
#define NB ((NN + 255) / 256)      // 196 node blocks
#define BINS ((NN + 255) / 256)    // 196 bins of 256 target nodes
#define CAPB 4608                  // bin capacity (mean 4096, +8 sigma)
#define EPB 2048                   // edges per binning block
#define GA ((NE + EPB - 1) / EPB)  // 391 binning blocks

typedef __hip_bfloat16 bf16;

__device__ inline float b2f(unsigned short u) {
    unsigned v = ((unsigned)u) << 16;
    return __uint_as_float(v);
}
__device__ inline unsigned short f2b(float f) {
    bf16 h = __float2bfloat16(f);
    return *reinterpret_cast<unsigned short*>(&h);
}

// zero bin counters + stats; graph start offsets from sorted batch
__global__ void k_prep(const int* __restrict__ batch, int* bin_cnt, float* stats,
                       int* starts) {
    int i = blockIdx.x * 256 + threadIdx.x;
    if (i < BINS) bin_cnt[i] = 0;
    if (i < 2 * CC) stats[i] = 0.0f;
    if (i < NN) {
        int b = batch[i];
        int bp = (i == 0) ? -1 : batch[i - 1];
        for (int g = bp + 1; g <= b; g++) starts[g] = i;
        if (i == NN - 1)
            for (int g = b + 1; g <= GG; g++) starts[g] = NN;
    }
}

// bin edges by target>>8; single pass over ei (col staged in LDS)
__global__ __launch_bounds__(256) void k_binA(const int* __restrict__ ei,
                                              const float* __restrict__ w,
                                              int* __restrict__ bin_cnt,
                                              int2* __restrict__ binbuf) {
    __shared__ int hist[BINS], base[BINS], rank[BINS];
    __shared__ int cstg[EPB];
    int t = threadIdx.x;
    for (int b = t; b < BINS; b += 256) { hist[b] = 0; rank[b] = 0; }
    __syncthreads();
    int e0 = blockIdx.x * EPB;
    for (int i = t; i < EPB; i += 256) {
        int e = e0 + i;
        if (e < NE) {
            int c = ei[NE + e];
            cstg[i] = c;
            atomicAdd(&hist[c >> 8], 1);
        }
    }
    __syncthreads();
    for (int b = t; b < BINS; b += 256)
        if (hist[b] > 0) base[b] = atomicAdd(&bin_cnt[b], hist[b]);
    __syncthreads();
    for (int i = t; i < EPB; i += 256) {
        int e = e0 + i;
        if (e >= NE) continue;
        int r = ei[e], c = cstg[i], b = c >> 8;
        int pos = base[b] + atomicAdd(&rank[b], 1);
        if (pos < CAPB)
            binbuf[(size_t)b * CAPB + pos] = make_int2(r | ((c & 255) << 16),
                                                       __float_as_int(w[e]));
    }
}

// one block per bin: LDS counting-sort by (target&255) -> per-node CSR (in place),
// fused weighted degree -> dinv. Zero device atomics.
__global__ __launch_bounds__(256) void k_csr(const int* __restrict__ bin_cnt,
                                             int2* __restrict__ binbuf,
                                             float* __restrict__ dinv,
                                             int* __restrict__ rps,
                                             int* __restrict__ rcnt) {
    __shared__ int2 ed[CAPB];
    __shared__ int hist[256], off[256], rank[256];
    __shared__ float degf[256];
    int g = blockIdx.x, t = threadIdx.x;
    int cnt = min(bin_cnt[g], CAPB);
    int2* bp = binbuf + (size_t)g * CAPB;
    hist[t] = 0; rank[t] = 0; degf[t] = 1.0f;   // deg starts at 1 (self-loop)
    __syncthreads();
    for (int e = t; e < cnt; e += 256) {
        int2 r = bp[e];
        ed[e] = r;
        int low = r.x >> 16;
        atomicAdd(&hist[low], 1);
        atomicAdd(&degf[low], __int_as_float(r.y));
    }
    __syncthreads();
    int v = hist[t];
    off[t] = v;
    __syncthreads();
    for (int o = 1; o < 256; o <<= 1) {        // inclusive scan
        int x = (t >= o) ? off[t - o] : 0;
        __syncthreads();
        off[t] += x;
        __syncthreads();
    }
    int node = g * 256 + t;
    if (node < NN) {
        dinv[node] = rsqrtf(degf[t]);
        rps[node] = g * CAPB + (off[t] - v);   // exclusive start
        rcnt[node] = v;
    }
    for (int e = t; e < cnt; e += 256) {
        int2 r = ed[e];
        int low = r.x >> 16;
        int pos = (off[low] - hist[low]) + atomicAdd(&rank[low], 1);
        bp[pos] = make_int2(r.x & 0xffff, r.y);
    }
}

// y = x @ W^T (bf16, no bias — bias commutes past the hops) + fold norm records
__global__ __launch_bounds__(256) void k_linfold(const float* __restrict__ x,
                                                 const float* __restrict__ W,
                                                 const float* __restrict__ dinv,
                                                 const int* __restrict__ rps,
                                                 const int* __restrict__ rcnt,
                                                 const int2* __restrict__ binbuf,
                                                 unsigned* __restrict__ csrc,
                                                 bf16* __restrict__ y) {
    __shared__ float Ws[CC * 65];
    __shared__ float hs[4][CC];
    int tid = threadIdx.x, wv = tid >> 6, j = tid & 63;
    for (int t = tid; t < CC * CC; t += 256)
        Ws[(t >> 6) * 65 + (t & 63)] = W[t];
    int node = blockIdx.x * 4 + wv;
    hs[wv][j] = (node < NN) ? x[node * CC + j] : 0.0f;
    __syncthreads();
    if (node >= NN) return;
    float acc = 0.0f;
    const float* hr = hs[wv];
#pragma unroll
    for (int k = 0; k < CC; k++) acc += hr[k] * Ws[j * 65 + k];
    y[node * CC + j] = __float2bfloat16(acc);
    // fold: csrc = src | bf16bits(dinv[src]*w*dinv[node])<<16
    float dn = dinv[node];
    int s = rps[node], n = rcnt[node];
    for (int p = j; p < n; p += 64) {
        int2 rec = binbuf[s + p];
        float nw = dinv[rec.x] * __int_as_float(rec.y) * dn;
        csrc[s + p] = (unsigned)rec.x | ((unsigned)f2b(nw) << 16);
    }
}

// wave per node, 4 edges per iteration: quarter-wave (16 lanes x ushort4) per edge.
__global__ __launch_bounds__(256) void k_hop5(const bf16* __restrict__ in,
                                              const float* __restrict__ dinv,
                                              const int* __restrict__ rps,
                                              const int* __restrict__ rcnt,
                                              const unsigned* __restrict__ csrc,
                                              bf16* __restrict__ out) {
    int node = blockIdx.x * 4 + (threadIdx.x >> 6);
    if (node >= NN) return;
    int lane = threadIdx.x & 63;
    int q = lane >> 4;             // 0..3: which edge of the quad
    int lc = lane & 15;            // channel-quad (channels 4lc..4lc+3)
    float dn = dinv[node];
    float a0 = 0.0f, a1 = 0.0f, a2 = 0.0f, a3 = 0.0f;
    if (q == 0) {                  // self-loop on quarter 0 only
        ushort4 sv = *reinterpret_cast<const ushort4*>(&in[node * CC + 4 * lc]);
        float d2 = dn * dn;
        a0 = d2 * b2f(sv.x); a1 = d2 * b2f(sv.y);
        a2 = d2 * b2f(sv.z); a3 = d2 * b2f(sv.w);
    }
    int s = rps[node], n = rcnt[node];
    const unsigned* cp = csrc + s;
    int p = 0;
#pragma unroll 2
    for (; p + 4 <= n; p += 4) {
        unsigned rec = cp[p + q];
        float nw = __uint_as_float(rec & 0xffff0000u);   // bf16 expand
        int src = rec & 0xffff;
        ushort4 v = *reinterpret_cast<const ushort4*>(&in[src * CC + 4 * lc]);
        a0 = fmaf(nw, b2f(v.x), a0); a1 = fmaf(nw, b2f(v.y), a1);
        a2 = fmaf(nw, b2f(v.z), a2); a3 = fmaf(nw, b2f(v.w), a3);
    }
    if (p < n && q < n - p) {      // tail: 1..3 edges on quarters 0..n-p-1
        unsigned rec = cp[p + q];
        float nw = __uint_as_float(rec & 0xffff0000u);
        int src = rec & 0xffff;
        ushort4 v = *reinterpret_cast<const ushort4*>(&in[src * CC + 4 * lc]);
        a0 = fmaf(nw, b2f(v.x), a0); a1 = fmaf(nw, b2f(v.y), a1);
        a2 = fmaf(nw, b2f(v.z), a2); a3 = fmaf(nw, b2f(v.w), a3);
    }
    // combine quarters
    a0 += __shfl_xor(a0, 16, 64); a1 += __shfl_xor(a1, 16, 64);
    a2 += __shfl_xor(a2, 16, 64); a3 += __shfl_xor(a3, 16, 64);
    a0 += __shfl_xor(a0, 32, 64); a1 += __shfl_xor(a1, 32, 64);
    a2 += __shfl_xor(a2, 32, 64); a3 += __shfl_xor(a3, 32, 64);
    if (q == 0) {
        ushort4 ov = make_ushort4(f2b(a0), f2b(a1), f2b(a2), f2b(a3));
        *reinterpret_cast<ushort4*>(&out[node * CC + 4 * lc]) = ov;
    }
}

// one block per graph: v = PReLU(h2+b); per-graph sum/max/min (raw v) +
// global per-channel sum/sumsq atomics. BN applied later in k_finish.
__global__ __launch_bounds__(256) void k_poolstat(const bf16* __restrict__ h,
                                                  const float* __restrict__ bvec,
                                                  const float* __restrict__ a,
                                                  const int* __restrict__ starts,
                                                  float* __restrict__ stats,
                                                  float* __restrict__ gsum,
                                                  float* __restrict__ gmax,
                                                  float* __restrict__ gmin) {
    __shared__ float r0[4][CC], r1[4][CC], r2[4][CC];
    int g = blockIdx.x;
    int s = starts[g], e = starts[g + 1];
    int tid = threadIdx.x, w = tid >> 6, j = tid & 63;
    float bs = bvec[j], as = a[j];
    float sum = 0.0f, sq = 0.0f, mx = -__builtin_inff(), mn = __builtin_inff();
    for (int i = s + w; i < e; i += 4) {
        float v = __bfloat162float(h[i * CC + j]) + bs;
        v = v >= 0.0f ? v : as * v;
        sum += v;
        sq += v * v;
        mx = fmaxf(mx, v);
        mn = fminf(mn, v);
    }
    r0[w][j] = sum; r1[w][j] = mx; r2[w][j] = mn;
    __syncthreads();
    if (w == 0) {
        sum = r0[0][j] + r0[1][j] + r0[2][j] + r0[3][j];
        mx = fmaxf(fmaxf(r1[0][j], r1[1][j]), fmaxf(r1[2][j], r1[3][j]));
        mn = fminf(fminf(r2[0][j], r2[1][j]), fminf(r2[2][j], r2[3][j]));
        gsum[g * CC + j] = sum;
        gmax[g * CC + j] = mx;
        gmin[g * CC + j] = mn;
        atomicAdd(&stats[j], sum);
    }
    __syncthreads();
    r0[w][j] = sq;
    __syncthreads();
    if (w == 0) {
        sq = r0[0][j] + r0[1][j] + r0[2][j] + r0[3][j];
        atomicAdd(&stats[CC + j], sq);
    }
}

// BN affine applied to pooled results: mean' = sc*mean+sh; max' = sc>0?sc*mx+sh:sc*mn+sh
__global__ void k_finish(const float* __restrict__ stats,
                         const float* __restrict__ gamma,
                         const float* __restrict__ beta,
                         const int* __restrict__ starts,
                         const float* __restrict__ gsum,
                         const float* __restrict__ gmax,
                         const float* __restrict__ gmin,
                         float* __restrict__ out) {
    int t = blockIdx.x * 256 + threadIdx.x;
    if (t >= GG * CC) return;
    int g = t >> 6, j = t & 63;
    float mean = stats[j] * (1.0f / NN);
    float var = stats[CC + j] * (1.0f / NN) - mean * mean;
    float sc = gamma[j] * rsqrtf(var + 1e-5f);
    float sh = beta[j] - mean * sc;
    int n = starts[g + 1] - starts[g];
    if (n > 0) {
        out[g * 2 * CC + j] = sc * (gsum[t] / (float)n) + sh;
        out[g * 2 * CC + CC + j] = (sc >= 0.0f) ? sc * gmax[t] + sh
                                                : sc * gmin[t] + sh;
    } else {
        out[g * 2 * CC + j] = 0.0f;
        out[g * 2 * CC + CC + j] = -__builtin_inff();
    }
}

extern "C" void kernel_launch(void* const* d_in, const int* in_sizes, int n_in,
                              void* d_out, int out_size, void* d_ws, size_t ws_size,
                              hipStream_t stream) {
    const float* x = (const float*)d_in[0];
    const int* ei = (const int*)d_in[1];
    const float* ew = (const float*)d_in[2];
    const int* batch = (const int*)d_in[3];
    const float* W = (const float*)d_in[4];
    const float* b = (const float*)d_in[5];
    const float* a = (const float*)d_in[6];
    const float* gamma = (const float*)d_in[7];
    const float* beta = (const float*)d_in[8];
    float* out = (float*)d_out;

    float* ws = (float*)d_ws;
    float* dinv = ws;
    int* rps = (int*)(ws + 50048);
    int* rcnt = (int*)(ws + 2 * 50048);
    int* bin_cnt = (int*)(ws + 3 * 50048);
    float* stats = ws + 3 * 50048 + 256;
    int* starts = (int*)(stats + 256);
    float* gsum = (float*)(starts + 256);
    float* gmax = gsum + GG * CC;
    float* gmin = gmax + GG * CC;
    int2* binbuf = (int2*)(gmin + GG * CC);
    unsigned* csrc = (unsigned*)(binbuf + (size_t)BINS * CAPB);
    bf16* y = (bf16*)(csrc + (size_t)BINS * CAPB);
    bf16* h1 = y + (size_t)NN * CC;
    bf16* h2 = h1 + (size_t)NN * CC;

    dim3 blk(256);
    int gH = (NN + 3) / 4;

    k_prep<<<NB, blk, 0, stream>>>(batch, bin_cnt, stats, starts);
    k_binA<<<GA, blk, 0, stream>>>(ei, ew, bin_cnt, binbuf);
    k_csr<<<BINS, blk, 0, stream>>>(bin_cnt, binbuf, dinv, rps, rcnt);
    k_linfold<<<gH, blk, 0, stream>>>(x, W, dinv, rps, rcnt, binbuf, csrc, y);

    k_hop5<<<gH, blk, 0, stream>>>(y, dinv, rps, rcnt, csrc, h1);
    k_hop5<<<gH, blk, 0, stream>>>(h1, dinv, rps, rcnt, csrc, h2);

    k_poolstat<<<GG, blk, 0, stream>>>(h2, b, a, starts, stats, gsum, gmax, gmin);
    k_finish<<<(GG * CC + 255) / 256, blk, 0, stream>>>(stats, gamma, beta, starts,
                                                        gsum, gmax, gmin, out);
}